// Round 4
// baseline (118.230 us; speedup 1.0000x reference)
//
#include <hip/hip_runtime.h>

// Problem: A=8, B=16, N=M=1024, K=64. u:(A,B,N,K) f32, v:(A,B,M,K) f32.
// out0 = u * (dot(u_row, v_sum) > 0), out1 = v * (dot(v_row, u_sum) > 0)
//
// Round-7: two-kernel split using the Infinity Cache as the inter-phase
// buffer. History: single-kernel variants serialize a read phase (~16 us,
// with 2x-issued reads partially L2-absorbed), a barrier middle, and a write
// phase (~10.7 us) -> ~29 us vs the 21.3 us floor (134 MB / 6.3 TB/s).
// Round-6's pairwise flag-exchange removed duplicate reads but its
// rendezvous cost >= the savings (30.7 us) -> duplicates were already
// L2-cheap; the gap is PHASE SERIALIZATION, not traffic.
//
// Fix: K1 streams u,v once (67 MB HBM, zero duplicates) -> block partial
// colsums -> 128 KB ws. K2 re-reads u,v (L3-resident: K1 just pulled them
// through the 256 MB memory-side cache, nothing evicts in between), combines
// the 2 half-partials per batch, masks, and streams 67 MB of nontemporal
// stores to HBM concurrently with the L3-served reads. HBM moves exactly
// 67R + 67W; K2 overlaps R and W. No barriers at all in K2, no spin
// anywhere, plain launches (graph-capture-safe).

#define NBATCH 128        // A*B
#define NROW   1024       // N == M
#define KDIM   64
#define ELEMS_PER_TENSOR (128ull * 1024ull * 64ull)  // 8388608

// ws: [batch][half][which][64 floats]; which: 0 = v colsum (masks u), 1 = u colsum
#define WS_PAYLOAD_FLOATS (NBATCH * 2 * 2 * 64)      // 32768 floats = 128 KB
#define WS_BYTES ((size_t)WS_PAYLOAD_FLOATS * 4)

typedef float floatx4 __attribute__((ext_vector_type(4)));  // for nontemporal builtin

// Shared bid -> (batch, half) mapping. Same in K1 and K2 so a (batch,half)'s
// data is re-read on the same XCD that fetched it (L2 affinity on top of L3).
__device__ __forceinline__ void decode_bid(int bid, int& batch, int& half) {
    const int xcd  = bid & 7;
    const int slot = bid >> 3;           // 0..31
    batch = xcd * 16 + (slot >> 1);      // 0..127
    half  = slot & 1;
}

// ---- K1: column sums (read-once, 67 MB HBM) -------------------------------
__global__ __launch_bounds__(1024)
void colsum_kernel(const float* __restrict__ u,
                   const float* __restrict__ v,
                   float4* __restrict__ ws) {
    int batch, half;
    decode_bid(blockIdx.x, batch, half);
    const int tid  = threadIdx.x;        // 0..1023
    const int k4   = tid & 15;           // float4 column group
    const int rg   = tid >> 4;           // 0..63 row group
    const int wave = tid >> 6;           // 0..15

    const float4* ub = (const float4*)(u + (size_t)batch * NROW * KDIM);
    const float4* vb = (const float4*)(v + (size_t)batch * NROW * KDIM);
    const int r0 = half * 512 + rg;

    float4 su = make_float4(0.f, 0.f, 0.f, 0.f);
    float4 sv = make_float4(0.f, 0.f, 0.f, 0.f);
    #pragma unroll
    for (int i = 0; i < 8; ++i) {
        size_t io = (size_t)(r0 + 64 * i) * 16 + k4;   // coalesced: wave = 4 rows x 1KB
        float4 a = ub[io];
        float4 b = vb[io];
        su.x += a.x; su.y += a.y; su.z += a.z; su.w += a.w;
        sv.x += b.x; sv.y += b.y; sv.z += b.z; sv.w += b.w;
    }

    // reduce across the 4 row-groups of each wave (lanes differ by 16/32)
    su.x += __shfl_xor(su.x, 16); su.y += __shfl_xor(su.y, 16);
    su.z += __shfl_xor(su.z, 16); su.w += __shfl_xor(su.w, 16);
    su.x += __shfl_xor(su.x, 32); su.y += __shfl_xor(su.y, 32);
    su.z += __shfl_xor(su.z, 32); su.w += __shfl_xor(su.w, 32);
    sv.x += __shfl_xor(sv.x, 16); sv.y += __shfl_xor(sv.y, 16);
    sv.z += __shfl_xor(sv.z, 16); sv.w += __shfl_xor(sv.w, 16);
    sv.x += __shfl_xor(sv.x, 32); sv.y += __shfl_xor(sv.y, 32);
    sv.z += __shfl_xor(sv.z, 32); sv.w += __shfl_xor(sv.w, 32);

    __shared__ float4 red_u[16][16];   // [wave][k4]
    __shared__ float4 red_v[16][16];
    if ((tid & 63) < 16) {             // lanes 0..15 hold k4 = lane
        red_u[wave][k4] = su;
        red_v[wave][k4] = sv;
    }
    __syncthreads();

    if (tid < 32) {
        const int which = tid >> 4;    // 0 -> v colsum, 1 -> u colsum
        const int c     = tid & 15;
        float4 t = make_float4(0.f, 0.f, 0.f, 0.f);
        if (which == 0) {
            #pragma unroll
            for (int i = 0; i < 16; ++i) {
                float4 b = red_v[i][c];
                t.x += b.x; t.y += b.y; t.z += b.z; t.w += b.w;
            }
        } else {
            #pragma unroll
            for (int i = 0; i < 16; ++i) {
                float4 a = red_u[i][c];
                t.x += a.x; t.y += a.y; t.z += a.z; t.w += a.w;
            }
        }
        ws[(((size_t)batch * 2 + half) * 2 + which) * 16 + c] = t;
    }
}

// ---- K2: combine partials, mask, stream stores (no barriers, no LDS) ------
__global__ __launch_bounds__(1024)
void mask_kernel(const float* __restrict__ u,
                 const float* __restrict__ v,
                 float* __restrict__ out,
                 const float4* __restrict__ ws) {
    int batch, half;
    decode_bid(blockIdx.x, batch, half);
    const int tid = threadIdx.x;
    const int k4  = tid & 15;
    const int rg  = tid >> 4;

    // colsum of both halves (tiny, L2-hot)
    const float4 vs0 = ws[(((size_t)batch * 2 + 0) * 2 + 0) * 16 + k4];
    const float4 vs1 = ws[(((size_t)batch * 2 + 1) * 2 + 0) * 16 + k4];
    const float4 us0 = ws[(((size_t)batch * 2 + 0) * 2 + 1) * 16 + k4];
    const float4 us1 = ws[(((size_t)batch * 2 + 1) * 2 + 1) * 16 + k4];
    const float4 vs = make_float4(vs0.x + vs1.x, vs0.y + vs1.y,
                                  vs0.z + vs1.z, vs0.w + vs1.w);  // masks u rows
    const float4 us = make_float4(us0.x + us1.x, us0.y + us1.y,
                                  us0.z + us1.z, us0.w + us1.w);  // masks v rows

    const size_t boff = (size_t)batch * NROW * KDIM;
    const float4* ub = (const float4*)(u + boff);
    const float4* vb = (const float4*)(v + boff);
    float* ou = out + boff;
    float* ov = out + ELEMS_PER_TENSOR + boff;
    const int r0 = half * 512 + rg;

    // ---- u: load 8 rows (L3-served), mask, nontemporal store --------------
    float4 ur[8];
    #pragma unroll
    for (int i = 0; i < 8; ++i)
        ur[i] = ub[(size_t)(r0 + 64 * i) * 16 + k4];
    #pragma unroll
    for (int i = 0; i < 8; ++i) {
        size_t io = (size_t)(r0 + 64 * i) * 16 + k4;
        float pu = ur[i].x * vs.x + ur[i].y * vs.y + ur[i].z * vs.z + ur[i].w * vs.w;
        pu += __shfl_xor(pu, 1);
        pu += __shfl_xor(pu, 2);
        pu += __shfl_xor(pu, 4);
        pu += __shfl_xor(pu, 8);
        float mu = (pu > 0.f) ? 1.f : 0.f;
        floatx4 outu = { ur[i].x * mu, ur[i].y * mu, ur[i].z * mu, ur[i].w * mu };
        __builtin_nontemporal_store(outu, (floatx4*)(ou + io * 4));
    }

    // ---- v: same, reusing registers; mixes reads with in-flight u-stores --
    float4 vr[8];
    #pragma unroll
    for (int i = 0; i < 8; ++i)
        vr[i] = vb[(size_t)(r0 + 64 * i) * 16 + k4];
    #pragma unroll
    for (int i = 0; i < 8; ++i) {
        size_t io = (size_t)(r0 + 64 * i) * 16 + k4;
        float pv = vr[i].x * us.x + vr[i].y * us.y + vr[i].z * us.z + vr[i].w * us.w;
        pv += __shfl_xor(pv, 1);
        pv += __shfl_xor(pv, 2);
        pv += __shfl_xor(pv, 4);
        pv += __shfl_xor(pv, 8);
        float mv = (pv > 0.f) ? 1.f : 0.f;
        floatx4 outv = { vr[i].x * mv, vr[i].y * mv, vr[i].z * mv, vr[i].w * mv };
        __builtin_nontemporal_store(outv, (floatx4*)(ov + io * 4));
    }
}

// ---- Fallback (round-1 single kernel): used only if ws is too small -------
__global__ __launch_bounds__(1024)
void fused_local_kernel(const float* __restrict__ u,
                        const float* __restrict__ v,
                        float* __restrict__ out) {
    int batch, half;
    decode_bid(blockIdx.x, batch, half);
    const int tid  = threadIdx.x;
    const int k4   = tid & 15;
    const int rg   = tid >> 4;
    const int wave = tid >> 6;

    const float4* ub = (const float4*)(u + (size_t)batch * NROW * KDIM);
    const float4* vb = (const float4*)(v + (size_t)batch * NROW * KDIM);

    const int r_own0 = half * 512 + rg;
    const int r_oth0 = (1 - half) * 512 + rg;

    float4 ur[8], vr[8];
    float4 su = make_float4(0.f, 0.f, 0.f, 0.f);
    float4 sv = make_float4(0.f, 0.f, 0.f, 0.f);
    #pragma unroll
    for (int i = 0; i < 8; ++i) {
        size_t io = (size_t)(r_own0 + 64 * i) * 16 + k4;
        ur[i] = ub[io];
        vr[i] = vb[io];
        su.x += ur[i].x; su.y += ur[i].y; su.z += ur[i].z; su.w += ur[i].w;
        sv.x += vr[i].x; sv.y += vr[i].y; sv.z += vr[i].z; sv.w += vr[i].w;
    }
    #pragma unroll
    for (int i = 0; i < 8; ++i) {
        size_t ix = (size_t)(r_oth0 + 64 * i) * 16 + k4;
        float4 a = ub[ix];
        float4 b = vb[ix];
        su.x += a.x; su.y += a.y; su.z += a.z; su.w += a.w;
        sv.x += b.x; sv.y += b.y; sv.z += b.z; sv.w += b.w;
    }

    su.x += __shfl_xor(su.x, 16); su.y += __shfl_xor(su.y, 16);
    su.z += __shfl_xor(su.z, 16); su.w += __shfl_xor(su.w, 16);
    su.x += __shfl_xor(su.x, 32); su.y += __shfl_xor(su.y, 32);
    su.z += __shfl_xor(su.z, 32); su.w += __shfl_xor(su.w, 32);
    sv.x += __shfl_xor(sv.x, 16); sv.y += __shfl_xor(sv.y, 16);
    sv.z += __shfl_xor(sv.z, 16); sv.w += __shfl_xor(sv.w, 16);
    sv.x += __shfl_xor(sv.x, 32); sv.y += __shfl_xor(sv.y, 32);
    sv.z += __shfl_xor(sv.z, 32); sv.w += __shfl_xor(sv.w, 32);

    __shared__ float4 red_u[16][16];
    __shared__ float4 red_v[16][16];
    __shared__ float4 fsum[2][16];
    if ((tid & 63) < 16) {
        red_u[wave][k4] = su;
        red_v[wave][k4] = sv;
    }
    __syncthreads();

    if (tid < 32) {
        const int which = tid >> 4;
        const int c     = tid & 15;
        float4 t = make_float4(0.f, 0.f, 0.f, 0.f);
        if (which == 0) {
            #pragma unroll
            for (int i = 0; i < 16; ++i) {
                float4 b = red_v[i][c];
                t.x += b.x; t.y += b.y; t.z += b.z; t.w += b.w;
            }
        } else {
            #pragma unroll
            for (int i = 0; i < 16; ++i) {
                float4 a = red_u[i][c];
                t.x += a.x; t.y += a.y; t.z += a.z; t.w += a.w;
            }
        }
        fsum[which][c] = t;
    }
    __syncthreads();

    const float4 vs = fsum[0][k4];
    const float4 us = fsum[1][k4];

    float* ou = out + (size_t)batch * NROW * KDIM;
    float* ov = out + ELEMS_PER_TENSOR + (size_t)batch * NROW * KDIM;

    #pragma unroll
    for (int i = 0; i < 8; ++i) {
        size_t io = (size_t)(r_own0 + 64 * i) * 16 + k4;

        float pu = ur[i].x * vs.x + ur[i].y * vs.y + ur[i].z * vs.z + ur[i].w * vs.w;
        pu += __shfl_xor(pu, 1);
        pu += __shfl_xor(pu, 2);
        pu += __shfl_xor(pu, 4);
        pu += __shfl_xor(pu, 8);
        float mu = (pu > 0.f) ? 1.f : 0.f;
        floatx4 outu = { ur[i].x * mu, ur[i].y * mu, ur[i].z * mu, ur[i].w * mu };
        __builtin_nontemporal_store(outu, (floatx4*)(ou + io * 4));

        float pv = vr[i].x * us.x + vr[i].y * us.y + vr[i].z * us.z + vr[i].w * us.w;
        pv += __shfl_xor(pv, 1);
        pv += __shfl_xor(pv, 2);
        pv += __shfl_xor(pv, 4);
        pv += __shfl_xor(pv, 8);
        float mv = (pv > 0.f) ? 1.f : 0.f;
        floatx4 outv = { vr[i].x * mv, vr[i].y * mv, vr[i].z * mv, vr[i].w * mv };
        __builtin_nontemporal_store(outv, (floatx4*)(ov + io * 4));
    }
}

extern "C" void kernel_launch(void* const* d_in, const int* in_sizes, int n_in,
                              void* d_out, int out_size, void* d_ws, size_t ws_size,
                              hipStream_t stream) {
    const float* u = (const float*)d_in[0];
    const float* v = (const float*)d_in[1];
    float* out = (float*)d_out;

    if (d_ws != nullptr && ws_size >= WS_BYTES) {
        float4* ws = (float4*)d_ws;
        colsum_kernel<<<dim3(256), dim3(1024), 0, stream>>>(u, v, ws);
        mask_kernel<<<dim3(256), dim3(1024), 0, stream>>>(u, v, out, ws);
    } else {
        fused_local_kernel<<<dim3(256), dim3(1024), 0, stream>>>(u, v, out);
    }
}

// Round 5
// 117.863 us; speedup vs baseline: 1.0031x; 1.0031x over previous
//
#include <hip/hip_runtime.h>

// Problem: A=8, B=16, N=M=1024, K=64. u:(A,B,N,K) f32, v:(A,B,M,K) f32.
// out0 = u * (dot(u_row, v_sum) > 0), out1 = v * (dot(v_row, u_sum) > 0)
//
// Round-8: overlap reads and writes INSIDE the single kernel (schedule fix,
// not traffic fix). History: R1 (same-XCD pair swizzle, read-all -> barrier
// -> write-all) = 28.8 us kernel; R3 (pairwise exchange) = 30.7; R4
// (two-kernel L3 split) = 32.8. Traffic-reduction attempts all lose to R1:
// post-swizzle duplicate reads are L2-absorbed. The remaining slack is the
// serialized bus: write path idle during the ~13 us read phase, read path
// idle during the ~10.7 us write phase.
//
// 3-act schedule (dependencies allow it):
//   A: read ALL of v (own half -> vr[8] regs, other half -> accumulate),
//      reduce -> v_colsum.                     [v: 67 MB issued, 33.5 unique]
//   B: stream u own rows: load -> mask(v_colsum) -> NT-store immediately,
//      accumulating u-colsum; then read u other half for the colsum.
//      u reads and u writes SHARE the bus.     [u reads + u writes overlap]
//   C: reduce u colsum, mask held vr[8], NT-store v.
//
// Reduce is now an all-thread LDS-broadcast self-reduce (threads with equal
// k4 read the same red[w][k4] address -> LDS broadcast, conflict-free), so
// only 2 barriers total (1 per colsum), no serial 32-thread phase.
// Only vr[8] (32 VGPRs) is held across phases; u rows are load-mask-store
// with short live ranges.

#define NBATCH 128        // A*B
#define NROW   1024       // N == M
#define KDIM   64
#define ELEMS_PER_TENSOR (128ull * 1024ull * 64ull)  // 8388608

typedef float floatx4 __attribute__((ext_vector_type(4)));  // for nontemporal builtin

__global__ __launch_bounds__(1024)
void fused_overlap_kernel(const float* __restrict__ u,
                          const float* __restrict__ v,
                          float* __restrict__ out) {
    const int bid   = blockIdx.x;        // 0..255 (1 block/CU)
    // Same-XCD pair swizzle: the two halves of a batch land on one XCD, so
    // the other-half reads hit lines the partner just pulled into that L2.
    const int xcd   = bid & 7;
    const int slot  = bid >> 3;          // 0..31
    const int batch = xcd * 16 + (slot >> 1);  // 0..127
    const int half  = slot & 1;          // own rows: [half*512, half*512+512)
    const int tid   = threadIdx.x;       // 0..1023
    const int k4    = tid & 15;          // float4 column group
    const int rg    = tid >> 4;          // 0..63 row group
    const int wave  = tid >> 6;          // 0..15

    const size_t boff = (size_t)batch * NROW * KDIM;
    const float4* ub = (const float4*)(u + boff);
    const float4* vb = (const float4*)(v + boff);
    float* ou = out + boff;
    float* ov = out + ELEMS_PER_TENSOR + boff;

    const int r_own0 = half * 512 + rg;
    const int r_oth0 = (1 - half) * 512 + rg;

    __shared__ float4 red_v[16][16];   // [wave][k4]
    __shared__ float4 red_u[16][16];

    // ================= Act A: v colsum (hold own v rows) ===================
    float4 vr[8];
    float4 sv = make_float4(0.f, 0.f, 0.f, 0.f);
    #pragma unroll
    for (int i = 0; i < 8; ++i) {
        size_t io = (size_t)(r_own0 + 64 * i) * 16 + k4;  // wave: 4 rows x 1KB, coalesced
        vr[i] = vb[io];
        sv.x += vr[i].x; sv.y += vr[i].y; sv.z += vr[i].z; sv.w += vr[i].w;
    }
    #pragma unroll
    for (int i = 0; i < 8; ++i) {
        size_t ix = (size_t)(r_oth0 + 64 * i) * 16 + k4;
        float4 b = vb[ix];
        sv.x += b.x; sv.y += b.y; sv.z += b.z; sv.w += b.w;
    }

    // reduce across the 4 row-groups within each wave (lane bits 4,5)
    sv.x += __shfl_xor(sv.x, 16); sv.y += __shfl_xor(sv.y, 16);
    sv.z += __shfl_xor(sv.z, 16); sv.w += __shfl_xor(sv.w, 16);
    sv.x += __shfl_xor(sv.x, 32); sv.y += __shfl_xor(sv.y, 32);
    sv.z += __shfl_xor(sv.z, 32); sv.w += __shfl_xor(sv.w, 32);
    if ((tid & 63) < 16)               // lanes 0..15 hold k4 = lane
        red_v[wave][k4] = sv;
    __syncthreads();                   // barrier 1

    // all-thread self-reduce: same-k4 threads read same address (broadcast)
    float4 vs = make_float4(0.f, 0.f, 0.f, 0.f);
    #pragma unroll
    for (int w = 0; w < 16; ++w) {
        float4 t = red_v[w][k4];
        vs.x += t.x; vs.y += t.y; vs.z += t.z; vs.w += t.w;
    }

    // ====== Act B: stream u own rows (load -> mask -> store), u colsum =====
    float4 su = make_float4(0.f, 0.f, 0.f, 0.f);
    #pragma unroll
    for (int i = 0; i < 8; ++i) {
        size_t io = (size_t)(r_own0 + 64 * i) * 16 + k4;
        float4 a = ub[io];
        su.x += a.x; su.y += a.y; su.z += a.z; su.w += a.w;
        float pu = a.x * vs.x + a.y * vs.y + a.z * vs.z + a.w * vs.w;
        pu += __shfl_xor(pu, 1);
        pu += __shfl_xor(pu, 2);
        pu += __shfl_xor(pu, 4);
        pu += __shfl_xor(pu, 8);       // full 64-col dot across the 16 k4 lanes
        float mu = (pu > 0.f) ? 1.f : 0.f;
        floatx4 outu = { a.x * mu, a.y * mu, a.z * mu, a.w * mu };
        __builtin_nontemporal_store(outu, (floatx4*)(ou + io * 4));
    }
    #pragma unroll
    for (int i = 0; i < 8; ++i) {
        size_t ix = (size_t)(r_oth0 + 64 * i) * 16 + k4;
        float4 a = ub[ix];
        su.x += a.x; su.y += a.y; su.z += a.z; su.w += a.w;
    }

    su.x += __shfl_xor(su.x, 16); su.y += __shfl_xor(su.y, 16);
    su.z += __shfl_xor(su.z, 16); su.w += __shfl_xor(su.w, 16);
    su.x += __shfl_xor(su.x, 32); su.y += __shfl_xor(su.y, 32);
    su.z += __shfl_xor(su.z, 32); su.w += __shfl_xor(su.w, 32);
    if ((tid & 63) < 16)
        red_u[wave][k4] = su;
    __syncthreads();                   // barrier 2

    float4 us = make_float4(0.f, 0.f, 0.f, 0.f);
    #pragma unroll
    for (int w = 0; w < 16; ++w) {
        float4 t = red_u[w][k4];
        us.x += t.x; us.y += t.y; us.z += t.z; us.w += t.w;
    }

    // ============ Act C: mask held v rows, stream stores ===================
    #pragma unroll
    for (int i = 0; i < 8; ++i) {
        size_t io = (size_t)(r_own0 + 64 * i) * 16 + k4;
        float pv = vr[i].x * us.x + vr[i].y * us.y + vr[i].z * us.z + vr[i].w * us.w;
        pv += __shfl_xor(pv, 1);
        pv += __shfl_xor(pv, 2);
        pv += __shfl_xor(pv, 4);
        pv += __shfl_xor(pv, 8);
        float mv = (pv > 0.f) ? 1.f : 0.f;
        floatx4 outv = { vr[i].x * mv, vr[i].y * mv, vr[i].z * mv, vr[i].w * mv };
        __builtin_nontemporal_store(outv, (floatx4*)(ov + io * 4));
    }
}

extern "C" void kernel_launch(void* const* d_in, const int* in_sizes, int n_in,
                              void* d_out, int out_size, void* d_ws, size_t ws_size,
                              hipStream_t stream) {
    const float* u = (const float*)d_in[0];
    const float* v = (const float*)d_in[1];
    float* out = (float*)d_out;

    fused_overlap_kernel<<<dim3(256), dim3(1024), 0, stream>>>(u, v, out);
}